// Round 2
// baseline (47.231 us; speedup 1.0000x reference)
//
#include <hip/hip_runtime.h>
#include <math.h>

#define PP 9       // K*K
#define CAPS 32
#define PS 16
#define HPS 8      // pose elems per thread (PS split across 2 threads)
#define OH 15
#define HH 32
#define WW 32
#define LN_2PI 1.8378770664093453f

#define SITES_PER_BLOCK 4
#define NXCD 8

__device__ __forceinline__ float frcp(float x) {
    float r;
    asm("v_rcp_f32 %0, %1" : "=v"(r) : "v"(x));
    return r;
}

// DPP helpers (VALU pipe): quad_perm xor1=0xB1, xor2=0x4E; row_ror:4=0x124, row_ror:8=0x128.
template <int CTRL>
__device__ __forceinline__ float dppf(float x) {
    int r = __builtin_amdgcn_update_dpp(0, __builtin_bit_cast(int, x), CTRL, 0xF, 0xF, true);
    return __builtin_bit_cast(float, r);
}
__device__ __forceinline__ float row_sum16(float x) {
    x += dppf<0xB1>(x);
    x += dppf<0x4E>(x);
    x += dppf<0x124>(x);
    x += dppf<0x128>(x);
    return x;
}
__device__ __forceinline__ float row_max16(float x) {
    x = fmaxf(x, dppf<0xB1>(x));
    x = fmaxf(x, dppf<0x4E>(x));
    x = fmaxf(x, dppf<0x124>(x));
    x = fmaxf(x, dppf<0x128>(x));
    return x;
}
// xor16 within each 32-lane group (and-mask 0x1F) -> halves stay independent.
__device__ __forceinline__ float swz_xor16(float x) {
    return __builtin_bit_cast(float,
        __builtin_amdgcn_ds_swizzle(__builtin_bit_cast(int, x), 0x401F));
}
// exchange with lane^32 (ds_bpermute spans the full 64-lane wave)
__device__ __forceinline__ float xhalf(float x) {
    return __shfl_xor(x, 32);
}

// Block = 256 threads = 4 waves = 4 CONSECUTIVE sites (L1 reuse of the
// overlapping 3x3 stride-2 windows: neighboring sites share a window column,
// neighboring rows share a window row). Blocks are XCD-swizzled so each XCD
// owns a contiguous run of 900 sites (= 4 full 15x15 images) -> shared pixels
// hit that XCD's L2 instead of being re-fetched per-XCD.
//
// Within a wave (split-PS layout, unchanged from R1): lane = half*32 + c;
// each thread owns 8 of the 16 pose elems of capsule c. Per-thread state
// v[9][8]+r[9]+mu[8]+is2[8] fits the 128-reg budget of (256,4): 4 waves/SIMD.
// Softmax over the 32 capsules stays inside each 32-lane half (both halves
// redundantly compute identical r[k]/a_out; cross-half adds are commutative
// so the halves agree bitwise). Cross-half sums: 9 shfl_xor(32) per E-step
// (ln-p partial over t) + 1 per M-step (sum of log sigma).
__global__ __launch_bounds__(256, 4) void emcaps_kernel(
    const float* __restrict__ x,      // (32,32,32,32,16)
    const float* __restrict__ a,      // (32,32,32,32)
    const float* __restrict__ wgt,    // (9,32,4,4)
    const float* __restrict__ beta_u, // (32)
    const float* __restrict__ beta_a, // (32)
    float* __restrict__ out_mu,       // (32,15,15,32,16)
    float* __restrict__ out_a)        // (32,15,15,32)
{
    const int tid = threadIdx.x;
    const int lane = tid & 63;
    const int wid = tid >> 6;       // wave id = which site of the block
    const int half = lane >> 5;     // which 8 pose elems
    const int c = lane & 31;        // capsule

    // XCD-aware bijective swizzle: 1800 blocks = 8 XCDs x 225 chunks.
    // Default dispatch round-robins blockIdx across XCDs; this remap gives
    // XCD x the contiguous site range [x*900, (x+1)*900).
    const int sb = (blockIdx.x & (NXCD - 1)) * 225 + (blockIdx.x >> 3);
    const int site = sb * SITES_PER_BLOCK + wid;

    const int j = site % OH;
    const int t2 = site / OH;
    const int i = t2 % OH;
    const int b = t2 / OH;
    const int h0 = 2 * i, w0 = 2 * j;

    // ---- phase 1: all global loads issued back-to-back ----
    float v[PP][HPS];  // holds x now; overwritten with votes in phase 2
    float r[PP];
    #pragma unroll
    for (int k = 0; k < PP; ++k) {
        const int hh = h0 + k / 3, ww = w0 + k % 3;
        const size_t pix = (size_t)(b * HH + hh) * WW + ww;
        const float* xb = x + pix * (CAPS * PS) + c * PS + half * HPS;
        *(float4*)&v[k][0] = *(const float4*)xb;
        *(float4*)&v[k][4] = *(const float4*)(xb + 4);
        r[k] = a[pix * CAPS + c] * (1.f / 32.f);  // initial r (it0)
    }

    // ---- phase 2: votes in place (weights are L1-hot: 18 KB total) ----
    // t = half*8 + u, p = t>>2, q-col = t&3:
    // vote[t] = sum_q x[p][q] * w[q][t&3]; x[p][q] lives at local (u&4)+q.
    #pragma unroll
    for (int k = 0; k < PP; ++k) {
        float xt[HPS];
        #pragma unroll
        for (int u = 0; u < HPS; ++u) xt[u] = v[k][u];
        float wl[PS];
        const float* wb = wgt + k * (CAPS * PS) + c * PS;
        *(float4*)&wl[0]  = *(const float4*)wb;
        *(float4*)&wl[4]  = *(const float4*)(wb + 4);
        *(float4*)&wl[8]  = *(const float4*)(wb + 8);
        *(float4*)&wl[12] = *(const float4*)(wb + 12);
        #pragma unroll
        for (int u = 0; u < HPS; ++u) {
            float acc = 0.f;
            #pragma unroll
            for (int q = 0; q < 4; ++q)
                acc = fmaf(xt[(u & 4) + q], wl[q * 4 + (u & 3)], acc);
            v[k][u] = acc;
        }
    }

    const float bu = beta_u[c];
    const float ba = beta_a[c];
    const float eps = 1e-6f;
    const float lam = 1e-3f;

    float mu[HPS], is2[HPS];   // is2 = 1/(2*sigma^2); sigma itself not kept
    float aoc = 0.f;
    float slgfull = 0.f;       // full sum over 16 t of 0.5*log(sigma^2)
    float r_sum;

    for (int it = 0; it < 3; ++it) {
        if (it > 0) {
            // ---- E-step ----
            const float addc = __logf(aoc) - slgfull - 8.f * LN_2PI;
            #pragma unroll
            for (int k = 0; k < PP; ++k) {
                float sacc = 0.f;
                #pragma unroll
                for (int u = 0; u < HPS; ++u) {
                    float d = v[k][u] - mu[u];
                    sacc = fmaf(d * d, is2[u], sacc);
                }
                sacc += xhalf(sacc);         // full 16-element sum
                const float lnk = addc - sacc;
                // softmax over c within this 32-lane half
                float mx = row_max16(lnk);
                mx = fmaxf(mx, swz_xor16(mx));
                float e = __expf(lnk - mx);
                float ss = row_sum16(e);
                ss += swz_xor16(ss);
                r[k] = e * frcp(ss);
            }
        }

        // ---- M-step: two-pass (numerically required) ----
        r_sum = 0.f;
        #pragma unroll
        for (int k = 0; k < PP; ++k) r_sum += r[k];
        const float invr = frcp(r_sum + eps);
        #pragma unroll
        for (int k = 0; k < PP; ++k) r[k] *= invr;  // coeff

        #pragma unroll
        for (int u = 0; u < HPS; ++u) {
            float m = 0.f;
            #pragma unroll
            for (int k = 0; k < PP; ++k) m = fmaf(r[k], v[k][u], m);
            mu[u] = m;
        }
        float slg = 0.f;
        #pragma unroll
        for (int u = 0; u < HPS; ++u) {
            float sacc = 0.f;
            #pragma unroll
            for (int k = 0; k < PP; ++k) {
                float d = v[k][u] - mu[u];
                sacc = fmaf(r[k] * d, d, sacc);
            }
            const float sg = sacc + eps;
            is2[u] = frcp(2.f * sg);
            slg += 0.5f * __logf(sg);
        }
        slgfull = slg + xhalf(slg);          // full 16-element sum
        const float ch = r_sum * (16.f * bu + slgfull);
        aoc = frcp(1.f + __expf(-lam * (ba - ch)));
    }

    // ---- outputs: each thread stores its 8 mu's (32B); half 0 stores a ----
    float* ob = out_mu + (size_t)site * (CAPS * PS) + c * PS + half * HPS;
    *(float4*)(ob + 0) = make_float4(mu[0], mu[1], mu[2], mu[3]);
    *(float4*)(ob + 4) = make_float4(mu[4], mu[5], mu[6], mu[7]);
    if (half == 0) out_a[(size_t)site * CAPS + c] = aoc;
}

extern "C" void kernel_launch(void* const* d_in, const int* in_sizes, int n_in,
                              void* d_out, int out_size, void* d_ws, size_t ws_size,
                              hipStream_t stream) {
    const float* x      = (const float*)d_in[0];
    const float* a      = (const float*)d_in[1];
    const float* wgt    = (const float*)d_in[2];
    const float* beta_u = (const float*)d_in[3];
    const float* beta_a = (const float*)d_in[4];

    float* out_mu = (float*)d_out;
    float* out_a  = (float*)d_out + (size_t)32 * OH * OH * CAPS * PS;  // 3,686,400

    const int n_sites = 32 * OH * OH;          // 7200
    const int n_blocks = n_sites / SITES_PER_BLOCK;  // 1800 = 8 * 225
    emcaps_kernel<<<n_blocks, 64 * SITES_PER_BLOCK, 0, stream>>>(
        x, a, wgt, beta_u, beta_a, out_mu, out_a);
}

// Round 3
// 38.205 us; speedup vs baseline: 1.2362x; 1.2362x over previous
//
#include <hip/hip_runtime.h>
#include <math.h>

#define PP 9       // K*K
#define CAPS 32
#define PS 16
#define OH 15
#define HH 32
#define WW 32
#define LN_2PI 1.8378770664093453f

typedef float f32x2 __attribute__((ext_vector_type(2)));

__device__ __forceinline__ float frcp(float x) {
    float r;
    asm("v_rcp_f32 %0, %1" : "=v"(r) : "v"(x));
    return r;
}
__device__ __forceinline__ f32x2 splat2(float x) {
    f32x2 r; r.x = x; r.y = x; return r;
}
__device__ __forceinline__ f32x2 pkfma(f32x2 a, f32x2 b, f32x2 c) {
    return __builtin_elementwise_fma(a, b, c);  // -> v_pk_fma_f32 (gfx950 packed fp32)
}

// DPP helpers (VALU pipe): quad_perm xor1=0xB1, xor2=0x4E; row_ror:4=0x124, row_ror:8=0x128.
template <int CTRL>
__device__ __forceinline__ float dppf(float x) {
    int r = __builtin_amdgcn_update_dpp(0, __builtin_bit_cast(int, x), CTRL, 0xF, 0xF, true);
    return __builtin_bit_cast(float, r);
}
__device__ __forceinline__ float row_sum16(float x) {
    x += dppf<0xB1>(x);
    x += dppf<0x4E>(x);
    x += dppf<0x124>(x);
    x += dppf<0x128>(x);
    return x;
}
__device__ __forceinline__ float row_max16(float x) {
    x = fmaxf(x, dppf<0xB1>(x));
    x = fmaxf(x, dppf<0x4E>(x));
    x = fmaxf(x, dppf<0x124>(x));
    x = fmaxf(x, dppf<0x128>(x));
    return x;
}
// xor16 within each 32-lane group (and-mask 0x1F) -> halves (= the 2 sites) stay independent.
__device__ __forceinline__ float swz_xor16(float x) {
    return __builtin_bit_cast(float,
        __builtin_amdgcn_ds_swizzle(__builtin_bit_cast(int, x), 0x401F));
}

// R0 layout (best bench: 39.7 us): one 64-lane wave = TWO sites (32 lanes each),
// lane = s*32 + c; each thread owns all 16 pose elems of capsule c of site s.
// The per-k softmax cross-lane chain is amortized over 2 sites per wave
// (the R1/R2 split-PS layout duplicated it per site: +31% measured busy-cycles).
//
// NEW vs R0: all pose-element math is packed f32x2 -> v_pk_fma_f32/v_pk_add_f32
// (gfx950 packed fp32, 2 FLOP-lanes/instr), halving the elementwise instruction
// count (votes, E-step d^2*is2, M-step mu/sigma). Softmax chain stays scalar.
// Also: 16 logf(sigma) -> 8 logf(sig.x*sig.y) per M-step (product >= 1e-12, safe).
__global__ __launch_bounds__(64, 2) void emcaps_kernel(
    const float* __restrict__ x,      // (32,32,32,32,16)
    const float* __restrict__ a,      // (32,32,32,32)
    const float* __restrict__ wgt,    // (9,32,4,4)
    const float* __restrict__ beta_u, // (32)
    const float* __restrict__ beta_a, // (32)
    float* __restrict__ out_mu,       // (32,15,15,32,16)
    float* __restrict__ out_a)        // (32,15,15,32)
{
    const int lane = threadIdx.x;   // 0..63
    const int s = lane >> 5;        // site within pair
    const int c = lane & 31;        // capsule

    const int site = blockIdx.x * 2 + s;
    const int j = site % OH;
    const int t2 = site / OH;
    const int i = t2 % OH;
    const int b = t2 / OH;
    const int h0 = 2 * i, w0 = 2 * j;

    // ---- phase 1: all global loads issued back-to-back ----
    f32x2 v[PP][8];    // holds x now; overwritten with votes in phase 2
    float r[PP];
    #pragma unroll
    for (int k = 0; k < PP; ++k) {
        const int hh = h0 + k / 3, ww = w0 + k % 3;
        const size_t pix = (size_t)(b * HH + hh) * WW + ww;
        const float* xb = x + pix * (CAPS * PS) + c * PS;
        *(float4*)&v[k][0] = *(const float4*)xb;
        *(float4*)&v[k][2] = *(const float4*)(xb + 4);
        *(float4*)&v[k][4] = *(const float4*)(xb + 8);
        *(float4*)&v[k][6] = *(const float4*)(xb + 12);
        r[k] = a[pix * CAPS + c] * (1.f / 32.f);  // initial r (it0)
    }

    // ---- phase 2: votes in place (weights are L1-hot: 18 KB total) ----
    // pair m covers t=(2m,2m+1): x row idx (t&12)+q = 4*(m>>1)+q (same for both
    // halves of the pair); weight pair = w2[q*2 + (m&1)].
    #pragma unroll
    for (int k = 0; k < PP; ++k) {
        float xt[PS];
        #pragma unroll
        for (int m = 0; m < 8; ++m) { xt[2 * m] = v[k][m].x; xt[2 * m + 1] = v[k][m].y; }
        f32x2 w2[8];
        const float* wb = wgt + k * (CAPS * PS) + c * PS;
        *(float4*)&w2[0] = *(const float4*)wb;
        *(float4*)&w2[2] = *(const float4*)(wb + 4);
        *(float4*)&w2[4] = *(const float4*)(wb + 8);
        *(float4*)&w2[6] = *(const float4*)(wb + 12);
        #pragma unroll
        for (int m = 0; m < 8; ++m) {
            f32x2 acc = splat2(0.f);
            #pragma unroll
            for (int q = 0; q < 4; ++q)
                acc = pkfma(splat2(xt[4 * (m >> 1) + q]), w2[q * 2 + (m & 1)], acc);
            v[k][m] = acc;
        }
    }

    const float bu = beta_u[c];
    const float ba = beta_a[c];
    const float eps = 1e-6f;
    const float lam = 1e-3f;

    f32x2 mu2[8], is22[8];   // is22 = 1/(2*sigma^2)
    float aoc = 0.f;
    float slgfull = 0.f;
    float r_sum;

    for (int it = 0; it < 3; ++it) {
        if (it > 0) {
            // ---- E-step ----
            const float addc = __logf(aoc) - slgfull - 8.f * LN_2PI;
            #pragma unroll
            for (int k = 0; k < PP; ++k) {
                f32x2 s2 = splat2(0.f);
                #pragma unroll
                for (int m = 0; m < 8; ++m) {
                    f32x2 d = v[k][m] - mu2[m];
                    s2 = pkfma(d * d, is22[m], s2);
                }
                const float sacc = s2.x + s2.y;
                const float lnk = addc - sacc;
                // softmax over c within this 32-lane half
                float mx = row_max16(lnk);
                mx = fmaxf(mx, swz_xor16(mx));
                float e = __expf(lnk - mx);
                float ss = row_sum16(e);
                ss += swz_xor16(ss);
                r[k] = e * frcp(ss);
            }
        }

        // ---- M-step: two-pass (numerically required) ----
        r_sum = 0.f;
        #pragma unroll
        for (int k = 0; k < PP; ++k) r_sum += r[k];
        const float invr = frcp(r_sum + eps);
        f32x2 rr[PP];
        #pragma unroll
        for (int k = 0; k < PP; ++k) { r[k] *= invr; rr[k] = splat2(r[k]); }

        #pragma unroll
        for (int m = 0; m < 8; ++m) {
            f32x2 acc = splat2(0.f);
            #pragma unroll
            for (int k = 0; k < PP; ++k) acc = pkfma(rr[k], v[k][m], acc);
            mu2[m] = acc;
        }
        float slg = 0.f;
        #pragma unroll
        for (int m = 0; m < 8; ++m) {
            f32x2 acc = splat2(0.f);
            #pragma unroll
            for (int k = 0; k < PP; ++k) {
                f32x2 d = v[k][m] - mu2[m];
                acc = pkfma(rr[k] * d, d, acc);
            }
            f32x2 sg = acc + splat2(eps);
            is22[m].x = frcp(2.f * sg.x);
            is22[m].y = frcp(2.f * sg.y);
            slg += 0.5f * __logf(sg.x * sg.y);   // = 0.5*(log sx + log sy)
        }
        slgfull = slg;
        const float ch = r_sum * (16.f * bu + slgfull);
        aoc = frcp(1.f + __expf(-lam * (ba - ch)));
    }

    // ---- outputs: each thread stores its 16 mu's (64B) + its a ----
    float* ob = out_mu + (size_t)site * (CAPS * PS) + c * PS;
    *(float4*)(ob + 0)  = *(float4*)&mu2[0];
    *(float4*)(ob + 4)  = *(float4*)&mu2[2];
    *(float4*)(ob + 8)  = *(float4*)&mu2[4];
    *(float4*)(ob + 12) = *(float4*)&mu2[6];
    out_a[(size_t)site * CAPS + c] = aoc;
}

extern "C" void kernel_launch(void* const* d_in, const int* in_sizes, int n_in,
                              void* d_out, int out_size, void* d_ws, size_t ws_size,
                              hipStream_t stream) {
    const float* x      = (const float*)d_in[0];
    const float* a      = (const float*)d_in[1];
    const float* wgt    = (const float*)d_in[2];
    const float* beta_u = (const float*)d_in[3];
    const float* beta_a = (const float*)d_in[4];

    float* out_mu = (float*)d_out;
    float* out_a  = (float*)d_out + (size_t)32 * OH * OH * CAPS * PS;  // 3,686,400

    const int n_sites = 32 * OH * OH;  // 7200
    emcaps_kernel<<<n_sites / 2, 64, 0, stream>>>(x, a, wgt, beta_u, beta_a, out_mu, out_a);
}